// Round 7
// baseline (361.912 us; speedup 1.0000x reference)
//
#include <hip/hip_runtime.h>

typedef _Float16 f16;
typedef __attribute__((ext_vector_type(8))) _Float16 f16x8;
typedef __attribute__((ext_vector_type(4))) float f32x4;

#define MFMA16(a, b, c) __builtin_amdgcn_mfma_f32_16x16x32_f16((a), (b), (c), 0, 0, 0)

__device__ __forceinline__ float silu_f(float x) {
    return x * __builtin_amdgcn_rcpf(1.f + __expf(-x));
}

__device__ __forceinline__ void pack4(f16* dst, float x0, float x1, float x2, float x3) {
    union { f16 h[4]; uint2 u; } p;
    p.h[0] = (f16)x0; p.h[1] = (f16)x1; p.h[2] = (f16)x2; p.h[3] = (f16)x3;
    *(uint2*)dst = p.u;
}

__device__ __forceinline__ int pkf16(float a, float b) {
    typedef __attribute__((ext_vector_type(2))) __fp16 fp16x2;
    union { fp16x2 v; int i; } u;
    u.v = __builtin_amdgcn_cvt_pkrtz(a, b);   // returns __fp16x2 on gfx950
    return u.i;
}

// ---------------------------------------------------------------------------
// 256 blocks x 512 threads (8 waves), 16 batch rows/block.
// 3 barriers/stage; no serial wave-0 section (L4+RK redundant on all waves);
// L1 B-frag formed in-register via ds_bpermute (no h0 LDS buffer).
//   D-frag lane (g,col): rows 4g+r (comp), col=batch  ->  RK state yreg/kreg
//   L1 B-frag lane (g,col): k=8g+j of batch col  <- lanes 16*(2g)+col, 16*(2g+1)+col
// ---------------------------------------------------------------------------
__global__ __launch_bounds__(512, 2) void ode_main(
        const float* __restrict__ y0, const float* __restrict__ tspan,
        const float* __restrict__ W1, const float* __restrict__ b1,
        const float* __restrict__ W2, const float* __restrict__ b2,
        const float* __restrict__ W3, const float* __restrict__ b3,
        const float* __restrict__ W4, const float* __restrict__ b4,
        float* __restrict__ out) {

    __shared__ f16 h1[16 * 264];
    __shared__ f16 h2[16 * 264];
    __shared__ f16 h3[16 * 136];
    __shared__ float bias[656];    // b1@0 b2@256 b3@512 b4@640, 652..655 = 0
    __shared__ float tsh[16];

    const int tid = threadIdx.x;
    const int l = tid & 63, w = tid >> 6;
    const int g = l >> 4, col = l & 15;
    const int blk = blockIdx.x;
    const int bp0 = (32 * g + col) * 4;    // byte addr of lane 16*(2g)+col
    const int bp1 = bp0 + 64;              // lane 16*(2g+1)+col

    // ---- persistent weight fragments ----
    f16x8 w1f[2], w2f[2][8], w3f[8], w4f[4];
#pragma unroll
    for (int a = 0; a < 2; ++a) {
        const int n = (2 * w + a) * 16 + col;
#pragma unroll
        for (int j = 0; j < 8; ++j) {
            const int k = g * 8 + j;
            w1f[a][j] = (k < 13) ? (f16)W1[k * 256 + n] : (f16)0.f;
        }
#pragma unroll
        for (int kt = 0; kt < 8; ++kt)
#pragma unroll
            for (int j = 0; j < 8; ++j)
                w2f[a][kt][j] = (f16)W2[(kt * 32 + g * 8 + j) * 256 + n];
    }
    {
        const int n3 = w * 16 + col;
#pragma unroll
        for (int kt = 0; kt < 8; ++kt)
#pragma unroll
            for (int j = 0; j < 8; ++j)
                w3f[kt][j] = (f16)W3[(kt * 32 + g * 8 + j) * 128 + n3];
    }
#pragma unroll
    for (int kt = 0; kt < 4; ++kt)
#pragma unroll
        for (int j = 0; j < 8; ++j)
            w4f[kt][j] = (col < 12) ? (f16)W4[(kt * 32 + g * 8 + j) * 12 + col] : (f16)0.f;

    // ---- LDS init ----
    for (int i = tid; i < 656; i += 512) {
        float v = 0.f;
        if (i < 256) v = b1[i];
        else if (i < 512) v = b2[i - 256];
        else if (i < 640) v = b3[i - 512];
        else if (i < 652) v = b4[i - 640];
        bias[i] = v;
    }
    if (tid < 16) tsh[tid] = tspan[tid];

    // ---- initial RK state in registers (comp c=4g+j of batch col) ----
    float yreg[4];
#pragma unroll
    for (int j = 0; j < 4; ++j) {
        const int c = 4 * g + j;
        yreg[j] = (c < 13) ? y0[(blk * 16 + col) * 13 + c] : 0.f;
    }
    if (w == 0) {
#pragma unroll
        for (int j = 0; j < 4; ++j) {
            const int c = 4 * g + j;
            if (c < 13) out[(size_t)(blk * 16 + col) * 13 + c] = yreg[j];
        }
    }
    __syncthreads();   // bias/tsh ready

    static constexpr float AT[5][5] = {
        {0.2f, 0.f, 0.f, 0.f, 0.f},
        {3.f/40.f, 9.f/40.f, 0.f, 0.f, 0.f},
        {44.f/45.f, -56.f/15.f, 32.f/9.f, 0.f, 0.f},
        {19372.f/6561.f, -25360.f/2187.f, 64448.f/6561.f, -212.f/729.f, 0.f},
        {9017.f/3168.f, -355.f/33.f, 46732.f/5247.f, 49.f/176.f, -5103.f/18656.f}
    };

    float kreg[6][4];
    f16x8 b0;
    {   // b0 from initial y
        int h01 = pkf16(yreg[0], yreg[1]), h23 = pkf16(yreg[2], yreg[3]);
        int u0 = __builtin_amdgcn_ds_bpermute(bp0, h01);
        int u1 = __builtin_amdgcn_ds_bpermute(bp0, h23);
        int u2 = __builtin_amdgcn_ds_bpermute(bp1, h01);
        int u3 = __builtin_amdgcn_ds_bpermute(bp1, h23);
        if (g >= 2) { u0 = 0; u1 = 0; u2 = 0; u3 = 0; }
        union { int i[4]; f16x8 v; } u; u.i[0]=u0; u.i[1]=u1; u.i[2]=u2; u.i[3]=u3;
        b0 = u.v;
    }

    for (int step = 0; step < 30; ++step) {
        const float hstep = (tsh[(step >> 1) + 1] - tsh[step >> 1]) * 0.5f;
#pragma unroll
        for (int s = 0; s < 6; ++s) {
            // ---- phase A: L1 (b0 in registers) -> h1 ----
            f32x4 acc[2];
#pragma unroll
            for (int a = 0; a < 2; ++a) acc[a] = (f32x4){0.f, 0.f, 0.f, 0.f};
#pragma unroll
            for (int a = 0; a < 2; ++a) acc[a] = MFMA16(w1f[a], b0, acc[a]);
#pragma unroll
            for (int a = 0; a < 2; ++a) {
                const int nt = 2 * w + a;
                float4 bb = *(const float4*)&bias[nt * 16 + g * 4];
                pack4(&h1[col * 264 + nt * 16 + g * 4],
                      silu_f(acc[a][0] + bb.x), silu_f(acc[a][1] + bb.y),
                      silu_f(acc[a][2] + bb.z), silu_f(acc[a][3] + bb.w));
            }
            __syncthreads();
            // ---- phase B: L2 ----
            f16x8 hf[8];
#pragma unroll
            for (int kt = 0; kt < 8; ++kt) hf[kt] = *(const f16x8*)&h1[col * 264 + kt * 32 + g * 8];
#pragma unroll
            for (int a = 0; a < 2; ++a) acc[a] = (f32x4){0.f, 0.f, 0.f, 0.f};
#pragma unroll
            for (int kt = 0; kt < 8; ++kt)
#pragma unroll
                for (int a = 0; a < 2; ++a) acc[a] = MFMA16(w2f[a][kt], hf[kt], acc[a]);
#pragma unroll
            for (int a = 0; a < 2; ++a) {
                const int nt = 2 * w + a;
                float4 bb = *(const float4*)&bias[256 + nt * 16 + g * 4];
                pack4(&h2[col * 264 + nt * 16 + g * 4],
                      silu_f(acc[a][0] + bb.x), silu_f(acc[a][1] + bb.y),
                      silu_f(acc[a][2] + bb.z), silu_f(acc[a][3] + bb.w));
            }
            __syncthreads();
            // ---- phase C: L3 ----
#pragma unroll
            for (int kt = 0; kt < 8; ++kt) hf[kt] = *(const f16x8*)&h2[col * 264 + kt * 32 + g * 8];
            f32x4 a3 = (f32x4){0.f, 0.f, 0.f, 0.f};
#pragma unroll
            for (int kt = 0; kt < 8; ++kt) a3 = MFMA16(w3f[kt], hf[kt], a3);
            {
                float4 bb = *(const float4*)&bias[512 + w * 16 + g * 4];
                pack4(&h3[col * 136 + w * 16 + g * 4],
                      silu_f(a3[0] + bb.x), silu_f(a3[1] + bb.y),
                      silu_f(a3[2] + bb.z), silu_f(a3[3] + bb.w));
            }
            __syncthreads();
            // ---- phase D: L4 + RK, redundant on ALL waves; no barrier after ----
            f16x8 h3f[4];
#pragma unroll
            for (int kt = 0; kt < 4; ++kt) h3f[kt] = *(const f16x8*)&h3[col * 136 + kt * 32 + g * 8];
            f32x4 a4 = (f32x4){0.f, 0.f, 0.f, 0.f};
#pragma unroll
            for (int kt = 0; kt < 4; ++kt) a4 = MFMA16(w4f[kt], h3f[kt], a4);
            float4 bb4 = *(const float4*)&bias[640 + g * 4];   // zeros for comps >= 12
            kreg[s][0] = a4[0] + bb4.x; kreg[s][1] = a4[1] + bb4.y;
            kreg[s][2] = a4[2] + bb4.z; kreg[s][3] = a4[3] + bb4.w;
            float x[4];
            if (s < 5) {
#pragma unroll
                for (int j = 0; j < 4; ++j) {
                    float a2 = 0.f;
#pragma unroll
                    for (int i = 0; i <= s; ++i) a2 += AT[s][i] * kreg[i][j];
                    x[j] = yreg[j] + hstep * a2;
                }
            } else {
#pragma unroll
                for (int j = 0; j < 4; ++j) {
                    float a2 = (35.f/384.f) * kreg[0][j] + (500.f/1113.f) * kreg[2][j]
                             + (125.f/192.f) * kreg[3][j] + (-2187.f/6784.f) * kreg[4][j]
                             + (11.f/84.f) * kreg[5][j];
                    yreg[j] += hstep * a2;
                    x[j] = yreg[j];
                }
                if ((step & 1) && w == 0) {
                    const int slot = (step + 1) >> 1;
#pragma unroll
                    for (int j = 0; j < 4; ++j) {
                        const int c = 4 * g + j;
                        if (c < 13)
                            out[((size_t)slot * 4096 + blk * 16 + col) * 13 + c] = yreg[j];
                    }
                }
            }
            // ---- rebuild b0 for next stage (in-register transpose) ----
            {
                int h01 = pkf16(x[0], x[1]), h23 = pkf16(x[2], x[3]);
                int u0 = __builtin_amdgcn_ds_bpermute(bp0, h01);
                int u1 = __builtin_amdgcn_ds_bpermute(bp0, h23);
                int u2 = __builtin_amdgcn_ds_bpermute(bp1, h01);
                int u3 = __builtin_amdgcn_ds_bpermute(bp1, h23);
                if (g >= 2) { u0 = 0; u1 = 0; u2 = 0; u3 = 0; }
                union { int i[4]; f16x8 v; } u; u.i[0]=u0; u.i[1]=u1; u.i[2]=u2; u.i[3]=u3;
                b0 = u.v;
            }
        }
    }
}

extern "C" void kernel_launch(void* const* d_in, const int* in_sizes, int n_in,
                              void* d_out, int out_size, void* d_ws, size_t ws_size,
                              hipStream_t stream) {
    (void)in_sizes; (void)n_in; (void)out_size; (void)d_ws; (void)ws_size;
    const float* y0 = (const float*)d_in[0];
    const float* ts = (const float*)d_in[1];
    const float* W1 = (const float*)d_in[2];
    const float* b1 = (const float*)d_in[3];
    const float* W2 = (const float*)d_in[4];
    const float* b2 = (const float*)d_in[5];
    const float* W3 = (const float*)d_in[6];
    const float* b3 = (const float*)d_in[7];
    const float* W4 = (const float*)d_in[8];
    const float* b4 = (const float*)d_in[9];
    float* out = (float*)d_out;

    hipLaunchKernelGGL(ode_main, dim3(256), dim3(512), 0, stream,
                       y0, ts, W1, b1, W2, b2, W3, b3, W4, b4, out);
}